// Round 1
// baseline (253.362 us; speedup 1.0000x reference)
//
#include <hip/hip_runtime.h>
#include <math.h>

#define LL 256
#define DD 64

// One block per (b,h,B) group. 512 threads = 8 waves.
// LDS: qT/kT transposed+XOR-swizzled [64][256] fp32 each + small arrays.
__launch_bounds__(512, 2)
__global__ void fused_attn_kernel(const float* __restrict__ q,
                                  const float* __restrict__ k,
                                  const float* __restrict__ Wq,
                                  const float* __restrict__ bq,
                                  const float* __restrict__ Wk,
                                  const float* __restrict__ bk,
                                  const float* __restrict__ W1,
                                  const float* __restrict__ W2a,
                                  const float* __restrict__ W2b,
                                  float* __restrict__ out)
{
    extern __shared__ float sm[];
    float* qT   = sm;                    // [64][256] swizzled: qT[d*256 + (i ^ (d&28))]
    float* kT   = sm + 64 * 256;         // [64][256] swizzled
    float* sPq  = sm + 2 * 64 * 256;     // [256] sum_d q[i][d]*Wq[d]
    float* sPk  = sPq + 256;             // [256]
    float* sPqk = sPk + 256;             // [256] q[i]·k[i]
    float* sTh  = sPqk + 256;            // [256] theta vector
    float* sSq  = sTh + 256;             // [256] Sigma_q
    float* sSk  = sSq + 256;             // [256] Sigma_k
    float* kwred= sSk + 256;             // [8][16][4] = 512
    float* kw_s = kwred + 512;           // [64]  kw[d] = sum_j W1[j]*k[j][d]
    float* sRed = kw_s + 64;             // [8] per-wave partials of theta scalar

    const int tid  = threadIdx.x;
    const int lane = tid & 63;
    const int wid  = tid >> 6;
    const int g    = blockIdx.x;
    const size_t gbase = (size_t)g * (LL * DD);
    const float4* q4 = (const float4*)(q + gbase);
    const float4* k4 = (const float4*)(k + gbase);

    // ---- Phase 0: stage q,k transposed into LDS; fuse row/col partial dots ----
    const int dc = tid & 15;                 // d-chunk (constant per thread: 512%16==0)
    const float4 wq4 = ((const float4*)Wq)[dc];
    const float4 wk4 = ((const float4*)Wk)[dc];

    float kw0 = 0.f, kw1 = 0.f, kw2 = 0.f, kw3 = 0.f;

#pragma unroll
    for (int it = 0; it < 8; ++it) {
        const int f = it * 512 + tid;
        const int j = f >> 4;                // row index
        const float4 vq = q4[f];
        const float4 vk = k4[f];
        const int db = dc * 4;
        const int p  = db & 28;              // same for db..db+3
        const int jx = j ^ p;
        qT[(db + 0) * 256 + jx] = vq.x;  kT[(db + 0) * 256 + jx] = vk.x;
        qT[(db + 1) * 256 + jx] = vq.y;  kT[(db + 1) * 256 + jx] = vk.y;
        qT[(db + 2) * 256 + jx] = vq.z;  kT[(db + 2) * 256 + jx] = vk.z;
        qT[(db + 3) * 256 + jx] = vq.w;  kT[(db + 3) * 256 + jx] = vk.w;

        const float w1j = W1[j];
        kw0 += w1j * vk.x; kw1 += w1j * vk.y; kw2 += w1j * vk.z; kw3 += w1j * vk.w;

        float pq  = vq.x * wq4.x + vq.y * wq4.y + vq.z * wq4.z + vq.w * wq4.w;
        float pk  = vk.x * wk4.x + vk.y * wk4.y + vk.z * wk4.z + vk.w * wk4.w;
        float pqk = vq.x * vk.x + vq.y * vk.y + vq.z * vk.z + vq.w * vk.w;
#pragma unroll
        for (int m = 1; m < 16; m <<= 1) {
            pq  += __shfl_xor(pq,  m);
            pk  += __shfl_xor(pk,  m);
            pqk += __shfl_xor(pqk, m);
        }
        if (dc == 0) { sPq[j] = pq; sPk[j] = pk; sPqk[j] = pqk; }
    }
    // kw partial: reduce lanes {l, l^16, l^32} (same dc) within wave
    kw0 += __shfl_xor(kw0, 16); kw0 += __shfl_xor(kw0, 32);
    kw1 += __shfl_xor(kw1, 16); kw1 += __shfl_xor(kw1, 32);
    kw2 += __shfl_xor(kw2, 16); kw2 += __shfl_xor(kw2, 32);
    kw3 += __shfl_xor(kw3, 16); kw3 += __shfl_xor(kw3, 32);
    if (lane < 16) {
        float4 kv; kv.x = kw0; kv.y = kw1; kv.z = kw2; kv.w = kw3;
        ((float4*)kwred)[wid * 16 + lane] = kv;   // kwred[wave][dc][e]
    }
    __syncthreads();

    if (tid < 64) {
        float s = 0.f;
#pragma unroll
        for (int w = 0; w < 8; ++w) s += kwred[w * 64 + tid];
        kw_s[tid] = s;
    }
    __syncthreads();

    // ---- Phase 1: theta[i], Sigma_q[i], Sigma_k[i] ----
    const float bq0 = bq[0], bk0 = bk[0];
    if (tid < 256) {
        const int i = tid;
        float qkw = 0.f;
#pragma unroll
        for (int d = 0; d < 64; ++d)
            qkw += qT[d * 256 + (i ^ (d & 28))] * kw_s[d];
        sTh[i] = qkw - W1[i] * sPqk[i];   // diagonal removed analytically
        sSq[i] = sPq[i] + bq0;
        sSk[i] = sPk[i] + bk0;
    }
    __syncthreads();

    // ---- Phase 2: hdn = W2a @ theta, leaky, dot with W2b -> scalar ----
    {
        const int o = tid >> 1, ih = tid & 1;
        const float4* wrow = (const float4*)W2a + o * 64 + ih * 32;
        const float4* th4  = (const float4*)sTh + ih * 32;
        float h = 0.f;
#pragma unroll 8
        for (int c = 0; c < 32; ++c) {
            const float4 wv = wrow[c];
            const float4 tv = th4[c];
            h += wv.x * tv.x + wv.y * tv.y + wv.z * tv.z + wv.w * tv.w;
        }
        h += __shfl_xor(h, 1);            // full hdn[o] on both lanes of pair
        float contrib = 0.f;
        if (ih == 0) {
            const float hl = (h >= 0.f) ? h : 0.1f * h;
            contrib = hl * W2b[o];
        }
#pragma unroll
        for (int m = 1; m < 64; m <<= 1) contrib += __shfl_xor(contrib, m);
        if (lane == 0) sRed[wid] = contrib;
    }
    __syncthreads();

    // ---- Phase 3: sim = q k^T, 8x16 tile per thread ----
    const int rg = tid >> 4;      // 0..31
    const int cg = tid & 15;      // 0..15
    const int i0 = rg * 8;

    float acc[8][16];
#pragma unroll
    for (int r = 0; r < 8; ++r)
#pragma unroll
        for (int c = 0; c < 16; ++c) acc[r][c] = 0.f;

#pragma unroll 4
    for (int kk = 0; kk < 64; ++kk) {
        const float* qr = qT + kk * 256;
        const float* kr = kT + kk * 256;
        const int p = kk & 28;
        const float4 qa = *(const float4*)(qr + ((i0    ) ^ p));
        const float4 qb = *(const float4*)(qr + ((i0 + 4) ^ p));
        float4 kf[4];
        kf[0] = *(const float4*)(kr + ((cg * 4      ) ^ p));
        kf[1] = *(const float4*)(kr + ((cg * 4 +  64) ^ p));
        kf[2] = *(const float4*)(kr + ((cg * 4 + 128) ^ p));
        kf[3] = *(const float4*)(kr + ((cg * 4 + 192) ^ p));
        const float qv[8] = {qa.x, qa.y, qa.z, qa.w, qb.x, qb.y, qb.z, qb.w};
#pragma unroll
        for (int r = 0; r < 8; ++r) {
#pragma unroll
            for (int m = 0; m < 4; ++m) {
                acc[r][m * 4 + 0] += qv[r] * kf[m].x;
                acc[r][m * 4 + 1] += qv[r] * kf[m].y;
                acc[r][m * 4 + 2] += qv[r] * kf[m].z;
                acc[r][m * 4 + 3] += qv[r] * kf[m].w;
            }
        }
    }

    // ---- Phase 4: logits, softmax over row, threshold mask, store ----
    const float th_sc = sRed[0] + sRed[1] + sRed[2] + sRed[3] +
                        sRed[4] + sRed[5] + sRed[6] + sRed[7];
    float sq[8];
#pragma unroll
    for (int r = 0; r < 8; ++r) sq[r] = sSq[i0 + r];
    float sk[16];
#pragma unroll
    for (int m = 0; m < 4; ++m)
#pragma unroll
        for (int e = 0; e < 4; ++e) sk[m * 4 + e] = sSk[m * 64 + cg * 4 + e];

    float* og = out + (size_t)g * (LL * LL);

#pragma unroll
    for (int r = 0; r < 8; ++r) {
        // pass 1: row max of logits
        float mx = -INFINITY;
#pragma unroll
        for (int c = 0; c < 16; ++c) {
            const float lg = acc[r][c] * sq[r] * sk[c];
            mx = fmaxf(mx, lg);
        }
        mx = fmaxf(mx, __shfl_xor(mx, 1));
        mx = fmaxf(mx, __shfl_xor(mx, 2));
        mx = fmaxf(mx, __shfl_xor(mx, 4));
        mx = fmaxf(mx, __shfl_xor(mx, 8));
        // pass 2: exp + masked numerator (mask commutes past the division)
        float sum = 0.f;
#pragma unroll
        for (int c = 0; c < 16; ++c) {
            const float lg = acc[r][c] * sq[r] * sk[c];
            const float pe = __expf(lg - mx);
            sum += pe;                                   // denominator unmasked
            acc[r][c] = (lg > th_sc) ? pe : 0.f;          // masked numerator
        }
        sum += __shfl_xor(sum, 1);
        sum += __shfl_xor(sum, 2);
        sum += __shfl_xor(sum, 4);
        sum += __shfl_xor(sum, 8);
        const float rinv = 1.0f / sum;
        const int row_off = (i0 + r) * 256 + cg * 4;
#pragma unroll
        for (int m = 0; m < 4; ++m) {
            float4 v;
            v.x = acc[r][m * 4 + 0] * rinv;
            v.y = acc[r][m * 4 + 1] * rinv;
            v.z = acc[r][m * 4 + 2] * rinv;
            v.w = acc[r][m * 4 + 3] * rinv;
            *(float4*)(og + row_off + m * 64) = v;
        }
    }
}

extern "C" void kernel_launch(void* const* d_in, const int* in_sizes, int n_in,
                              void* d_out, int out_size, void* d_ws, size_t ws_size,
                              hipStream_t stream) {
    const float* q   = (const float*)d_in[0];
    const float* k   = (const float*)d_in[1];
    const float* Wq  = (const float*)d_in[2];
    const float* bq  = (const float*)d_in[3];
    const float* Wk  = (const float*)d_in[4];
    const float* bk  = (const float*)d_in[5];
    const float* W1  = (const float*)d_in[6];
    const float* W2a = (const float*)d_in[7];
    const float* W2b = (const float*)d_in[8];
    float* out = (float*)d_out;

    const int ngroup = in_sizes[0] / (LL * DD);   // 512
    const size_t lds_bytes = (2 * 64 * 256 + 2120) * sizeof(float);  // 139552 B

    // Allow >64KB dynamic LDS (no-op if already allowed); harmless per call.
    (void)hipFuncSetAttribute((const void*)fused_attn_kernel,
                              hipFuncAttributeMaxDynamicSharedMemorySize,
                              (int)lds_bytes);

    fused_attn_kernel<<<dim3(ngroup), dim3(512), lds_bytes, stream>>>(
        q, k, Wq, bq, Wk, bk, W1, W2a, W2b, out);
}

// Round 2
// 226.952 us; speedup vs baseline: 1.1164x; 1.1164x over previous
//
#include <hip/hip_runtime.h>
#include <math.h>

#define LL 256
#define DD 64

typedef __attribute__((ext_vector_type(8))) short bf16x8;
typedef __attribute__((ext_vector_type(4))) float f32x4;

static __device__ __forceinline__ unsigned short f2bf(float f) {
    union { float f; unsigned u; } v; v.f = f;
    unsigned r = v.u + 0x7fffu + ((v.u >> 16) & 1u);
    return (unsigned short)(r >> 16);
}
static __device__ __forceinline__ float bf2f(unsigned short h) {
    union { unsigned u; float f; } v; v.u = ((unsigned)h) << 16;
    return v.f;
}

// One block per (b,h,B) group. 512 threads = 8 waves; wave w owns output rows
// [32w, 32w+32) = two 16-row MFMA tile-rows, all 256 cols.
__launch_bounds__(512, 2)
__global__ void fused_attn_mfma(const float* __restrict__ q,
                                const float* __restrict__ k,
                                const float* __restrict__ Wq,
                                const float* __restrict__ bq,
                                const float* __restrict__ Wk,
                                const float* __restrict__ bk,
                                const float* __restrict__ W1,
                                const float* __restrict__ W2a,
                                const float* __restrict__ W2b,
                                float* __restrict__ out)
{
    extern __shared__ char smc[];
    // k staged as bf16 hi/lo, row-major [256][64], XOR-swizzled byte^=(row&7)<<4
    unsigned short* kHi = (unsigned short*)smc;             // 32768 B
    unsigned short* kLo = (unsigned short*)(smc + 32768);   // 32768 B
    float* sPq  = (float*)(smc + 65536);  // [256] q[i]·Wq
    float* sPk  = sPq + 256;              // [256] k[i]·Wk
    float* sPqk = sPk + 256;              // [256] q[i]·k[i]
    float* sTh  = sPqk + 256;             // [256] theta vector
    float* sSq  = sTh + 256;              // [256] Sigma_q
    float* sSk  = sSq + 256;              // [256] Sigma_k
    float* kwred= sSk + 256;              // [8][64]
    float* kw_s = kwred + 512;            // [64] sum_j W1[j] k[j][d]
    float* sRed = kw_s + 64;              // [8]

    const int tid  = threadIdx.x;
    const int lane = tid & 63;
    const int wid  = tid >> 6;
    const int r16  = lane & 15;
    const int g4   = lane >> 4;
    const int rbase = wid * 32;
    const int gidx = blockIdx.x;
    const size_t gbase = (size_t)gidx * (LL * DD);
    const float* qg = q + gbase;
    const float4* q4 = (const float4*)qg;
    const float4* k4 = (const float4*)(k + gbase);

    // ---- issue A-operand (q) loads in MFMA fragment layout, early ----
    // A frag for 16x16x32: row = lane&15 (within tile), k(d) = (lane>>4)*8 + e
    float4 aq[2][2][2];   // [tile_row][kk][half]
#pragma unroll
    for (int tr = 0; tr < 2; ++tr)
#pragma unroll
        for (int kk = 0; kk < 2; ++kk) {
            const float* p = qg + (rbase + tr * 16 + r16) * DD + kk * 32 + g4 * 8;
            aq[tr][kk][0] = ((const float4*)p)[0];
            aq[tr][kk][1] = ((const float4*)p)[1];
        }

    // ---- phase 0: stream q,k; stage k_hi/k_lo to LDS; small dot products ----
    const int dc = tid & 15;              // d-chunk
    const float4 wq4 = ((const float4*)Wq)[dc];
    const float4 wk4 = ((const float4*)Wk)[dc];
    float kw0 = 0.f, kw1 = 0.f, kw2 = 0.f, kw3 = 0.f;

#pragma unroll
    for (int it = 0; it < 8; ++it) {
        const int f = it * 512 + tid;
        const int j = f >> 4;             // row
        const float4 vq = q4[f];
        const float4 vk = k4[f];

        const int sw = (j & 7) << 4;
        const int boff = j * 128 + ((dc * 8) ^ sw);
        const unsigned short h0 = f2bf(vk.x), h1 = f2bf(vk.y),
                             h2 = f2bf(vk.z), h3 = f2bf(vk.w);
        uint2 hv, lv;
        hv.x = (unsigned)h0 | ((unsigned)h1 << 16);
        hv.y = (unsigned)h2 | ((unsigned)h3 << 16);
        const unsigned short l0 = f2bf(vk.x - bf2f(h0)), l1 = f2bf(vk.y - bf2f(h1)),
                             l2 = f2bf(vk.z - bf2f(h2)), l3 = f2bf(vk.w - bf2f(h3));
        lv.x = (unsigned)l0 | ((unsigned)l1 << 16);
        lv.y = (unsigned)l2 | ((unsigned)l3 << 16);
        *(uint2*)((char*)kHi + boff) = hv;
        *(uint2*)((char*)kLo + boff) = lv;

        const float w1j = W1[j];
        kw0 += w1j * vk.x; kw1 += w1j * vk.y; kw2 += w1j * vk.z; kw3 += w1j * vk.w;

        float pq  = vq.x * wq4.x + vq.y * wq4.y + vq.z * wq4.z + vq.w * wq4.w;
        float pk  = vk.x * wk4.x + vk.y * wk4.y + vk.z * wk4.z + vk.w * wk4.w;
        float pqk = vq.x * vk.x + vq.y * vk.y + vq.z * vk.z + vq.w * vk.w;
#pragma unroll
        for (int m = 1; m < 16; m <<= 1) {
            pq  += __shfl_xor(pq,  m);
            pk  += __shfl_xor(pk,  m);
            pqk += __shfl_xor(pqk, m);
        }
        if (dc == 0) { sPq[j] = pq; sPk[j] = pk; sPqk[j] = pqk; }
    }
    kw0 += __shfl_xor(kw0, 16); kw0 += __shfl_xor(kw0, 32);
    kw1 += __shfl_xor(kw1, 16); kw1 += __shfl_xor(kw1, 32);
    kw2 += __shfl_xor(kw2, 16); kw2 += __shfl_xor(kw2, 32);
    kw3 += __shfl_xor(kw3, 16); kw3 += __shfl_xor(kw3, 32);
    if (lane < 16) {
        float4 kv; kv.x = kw0; kv.y = kw1; kv.z = kw2; kv.w = kw3;
        ((float4*)kwred)[wid * 16 + lane] = kv;
    }

    // ---- convert A frags to bf16 hi/lo (fp32 floats no longer needed) ----
    bf16x8 qhi[2][2], qlo[2][2];
#pragma unroll
    for (int tr = 0; tr < 2; ++tr)
#pragma unroll
        for (int kk = 0; kk < 2; ++kk) {
            const float fv[8] = {aq[tr][kk][0].x, aq[tr][kk][0].y, aq[tr][kk][0].z, aq[tr][kk][0].w,
                                 aq[tr][kk][1].x, aq[tr][kk][1].y, aq[tr][kk][1].z, aq[tr][kk][1].w};
#pragma unroll
            for (int e = 0; e < 8; ++e) {
                const unsigned short h = f2bf(fv[e]);
                qhi[tr][kk][e] = (short)h;
                qlo[tr][kk][e] = (short)f2bf(fv[e] - bf2f(h));
            }
        }

    __syncthreads();                                   // B1: k staged, kwred done
    if (tid < 64) {
        float s = 0.f;
#pragma unroll
        for (int w = 0; w < 8; ++w) s += kwred[w * 64 + tid];
        kw_s[tid] = s;
    }
    __syncthreads();                                   // B2: kw_s visible

    // ---- phase 1: theta[i] = q_i·kw - W1[i]*(q_i·k_i); Sigma_q/k ----
    const float bq0 = bq[0], bk0 = bk[0];
#pragma unroll
    for (int tr = 0; tr < 2; ++tr) {
        const int row = rbase + tr * 16 + r16;
        float s = 0.f;
#pragma unroll
        for (int kk = 0; kk < 2; ++kk) {
            const int d0 = kk * 32 + g4 * 8;
#pragma unroll
            for (int e = 0; e < 8; ++e) {
                const float qf = bf2f((unsigned short)qhi[tr][kk][e]) +
                                 bf2f((unsigned short)qlo[tr][kk][e]);
                s += qf * kw_s[d0 + e];
            }
        }
        s += __shfl_xor(s, 16);
        s += __shfl_xor(s, 32);
        if (g4 == 0) {
            sTh[row] = s - W1[row] * sPqk[row];
            sSq[row] = sPq[row] + bq0;
            sSk[row] = sPk[row] + bk0;
        }
    }
    __syncthreads();                                   // B3: sTh/sSq/sSk visible

    // ---- phase 2: hdn = W2a @ theta, leaky(0.1), dot W2b -> scalar ----
    {
        const int o = tid >> 1, ih = tid & 1;
        const float4* wrow = (const float4*)W2a + o * 64 + ih * 32;
        const float4* th4  = (const float4*)sTh + ih * 32;
        float h = 0.f;
#pragma unroll 8
        for (int c = 0; c < 32; ++c) {
            const float4 wv = wrow[c];
            const float4 tv = th4[c];
            h += wv.x * tv.x + wv.y * tv.y + wv.z * tv.z + wv.w * tv.w;
        }
        h += __shfl_xor(h, 1);
        float contrib = 0.f;
        if (ih == 0) {
            const float hl = (h >= 0.f) ? h : 0.1f * h;
            contrib = hl * W2b[o];
        }
#pragma unroll
        for (int m = 1; m < 64; m <<= 1) contrib += __shfl_xor(contrib, m);
        if (lane == 0) sRed[wid] = contrib;
    }
    __syncthreads();                                   // B4: sRed visible

    // ---- phase 3: sim = q k^T via 4-term bf16-split MFMA ----
    f32x4 acc[2][16];
#pragma unroll
    for (int tr = 0; tr < 2; ++tr)
#pragma unroll
        for (int ct = 0; ct < 16; ++ct)
            acc[tr][ct] = (f32x4){0.f, 0.f, 0.f, 0.f};

#pragma unroll
    for (int ct = 0; ct < 16; ++ct) {
        const int rowk = ct * 16 + r16;
        const int sw = (rowk & 7) << 4;
        const char* ph = (const char*)kHi + rowk * 128;
        const char* pl = (const char*)kLo + rowk * 128;
        const bf16x8 bh0 = *(const bf16x8*)(ph + ((g4 * 16) ^ sw));
        const bf16x8 bh1 = *(const bf16x8*)(ph + ((64 + g4 * 16) ^ sw));
        const bf16x8 bl0 = *(const bf16x8*)(pl + ((g4 * 16) ^ sw));
        const bf16x8 bl1 = *(const bf16x8*)(pl + ((64 + g4 * 16) ^ sw));
#pragma unroll
        for (int tr = 0; tr < 2; ++tr) {
            f32x4 c = acc[tr][ct];
            c = __builtin_amdgcn_mfma_f32_16x16x32_bf16(qhi[tr][0], bh0, c, 0, 0, 0);
            c = __builtin_amdgcn_mfma_f32_16x16x32_bf16(qhi[tr][1], bh1, c, 0, 0, 0);
            c = __builtin_amdgcn_mfma_f32_16x16x32_bf16(qhi[tr][0], bl0, c, 0, 0, 0);
            c = __builtin_amdgcn_mfma_f32_16x16x32_bf16(qhi[tr][1], bl1, c, 0, 0, 0);
            c = __builtin_amdgcn_mfma_f32_16x16x32_bf16(qlo[tr][0], bh0, c, 0, 0, 0);
            c = __builtin_amdgcn_mfma_f32_16x16x32_bf16(qlo[tr][1], bh1, c, 0, 0, 0);
            c = __builtin_amdgcn_mfma_f32_16x16x32_bf16(qlo[tr][0], bl0, c, 0, 0, 0);
            c = __builtin_amdgcn_mfma_f32_16x16x32_bf16(qlo[tr][1], bl1, c, 0, 0, 0);
            acc[tr][ct] = c;
        }
    }

    // ---- phase 4: logits, row softmax (unmasked denom), threshold, store ----
    const float th_sc = sRed[0] + sRed[1] + sRed[2] + sRed[3] +
                        sRed[4] + sRed[5] + sRed[6] + sRed[7];
    float skv[16];
#pragma unroll
    for (int ct = 0; ct < 16; ++ct) skv[ct] = sSk[ct * 16 + r16];

    float* og = out + (size_t)gidx * (LL * LL);
#pragma unroll
    for (int tr = 0; tr < 2; ++tr) {
#pragma unroll
        for (int r = 0; r < 4; ++r) {
            const int row = rbase + tr * 16 + g4 * 4 + r;   // C/D: row=(lane>>4)*4+reg
            const float sq = sSq[row];
            float lg[16];
            float mx = -INFINITY;
#pragma unroll
            for (int ct = 0; ct < 16; ++ct) {
                lg[ct] = acc[tr][ct][r] * sq * skv[ct];
                mx = fmaxf(mx, lg[ct]);
            }
            mx = fmaxf(mx, __shfl_xor(mx, 1));
            mx = fmaxf(mx, __shfl_xor(mx, 2));
            mx = fmaxf(mx, __shfl_xor(mx, 4));
            mx = fmaxf(mx, __shfl_xor(mx, 8));
            float sum = 0.f;
#pragma unroll
            for (int ct = 0; ct < 16; ++ct) {
                const float pe = __expf(lg[ct] - mx);
                sum += pe;                                  // unmasked denominator
                lg[ct] = (lg[ct] > th_sc) ? pe : 0.f;       // masked numerator
            }
            sum += __shfl_xor(sum, 1);
            sum += __shfl_xor(sum, 2);
            sum += __shfl_xor(sum, 4);
            sum += __shfl_xor(sum, 8);
            const float rinv = 1.0f / sum;
#pragma unroll
            for (int ct = 0; ct < 16; ++ct)
                og[row * LL + ct * 16 + r16] = lg[ct] * rinv;
        }
    }
}

extern "C" void kernel_launch(void* const* d_in, const int* in_sizes, int n_in,
                              void* d_out, int out_size, void* d_ws, size_t ws_size,
                              hipStream_t stream) {
    const float* q   = (const float*)d_in[0];
    const float* k   = (const float*)d_in[1];
    const float* Wq  = (const float*)d_in[2];
    const float* bq  = (const float*)d_in[3];
    const float* Wk  = (const float*)d_in[4];
    const float* bk  = (const float*)d_in[5];
    const float* W1  = (const float*)d_in[6];
    const float* W2a = (const float*)d_in[7];
    const float* W2b = (const float*)d_in[8];
    float* out = (float*)d_out;

    const int ngroup = in_sizes[0] / (LL * DD);        // 512
    const size_t lds_bytes = 65536 + 2120 * sizeof(float);  // 74016 B

    (void)hipFuncSetAttribute((const void*)fused_attn_mfma,
                              hipFuncAttributeMaxDynamicSharedMemorySize,
                              (int)lds_bytes);

    fused_attn_mfma<<<dim3(ngroup), dim3(512), lds_bytes, stream>>>(
        q, k, Wq, bq, Wk, bk, W1, W2a, W2b, out);
}